// Round 1
// baseline (1246.426 us; speedup 1.0000x reference)
//
#include <hip/hip_runtime.h>
#include <hip/hip_bf16.h>

#define T_DIM 1024
#define H_DIM 2048
#define F_DIM 4096
#define E_DIM 8

typedef unsigned short u16;
typedef unsigned int u32;
typedef __attribute__((ext_vector_type(8))) short bf16x8;
typedef __attribute__((ext_vector_type(4))) float f32x4;

// round-to-nearest-even fp32 -> bf16 (raw bits)
__device__ __forceinline__ u16 f2bf(float f) {
  u32 u = __builtin_bit_cast(u32, f);
  u32 r = (u + 0x7fffu + ((u >> 16) & 1u)) >> 16;
  return (u16)r;
}

// ---------------------------------------------------------------------------
// Kernel 1: gate logits + top-2 weights (exact reference emulation) + x->bf16
// grid: T/4 blocks x 256 threads; one wave per token.
// ---------------------------------------------------------------------------
__global__ __launch_bounds__(256) void gate_cvt_kernel(
    const float* __restrict__ x, const float* __restrict__ wg,
    u16* __restrict__ xb, float* __restrict__ wts) {
  int wave = threadIdx.x >> 6;
  int lane = threadIdx.x & 63;
  int t = blockIdx.x * 4 + wave;
  const float4* x4 = reinterpret_cast<const float4*>(x) + (size_t)t * 512;
  ushort4* xb4 = reinterpret_cast<ushort4*>(xb) + (size_t)t * 512;
  const float4* wg4 = reinterpret_cast<const float4*>(wg);

  float acc[8];
#pragma unroll
  for (int e = 0; e < 8; e++) acc[e] = 0.f;

#pragma unroll
  for (int i = 0; i < 8; i++) {
    int idx = i * 64 + lane;                 // float4 index within row (0..511)
    float4 v = x4[idx];
    ushort4 o = {f2bf(v.x), f2bf(v.y), f2bf(v.z), f2bf(v.w)};
    xb4[idx] = o;
    float xs[4] = {v.x, v.y, v.z, v.w};
    int hbase = idx * 4;
#pragma unroll
    for (int j = 0; j < 4; j++) {
      float4 wa = wg4[(hbase + j) * 2];
      float4 wb = wg4[(hbase + j) * 2 + 1];
      acc[0] += xs[j] * wa.x; acc[1] += xs[j] * wa.y;
      acc[2] += xs[j] * wa.z; acc[3] += xs[j] * wa.w;
      acc[4] += xs[j] * wb.x; acc[5] += xs[j] * wb.y;
      acc[6] += xs[j] * wb.z; acc[7] += xs[j] * wb.w;
    }
  }
  // wave-64 reduction per expert
#pragma unroll
  for (int e = 0; e < 8; e++) {
#pragma unroll
    for (int off = 32; off > 0; off >>= 1) acc[e] += __shfl_xor(acc[e], off, 64);
  }
  if (lane == 0) {
    const float NEG_MIN = -3.402823466e38f;
    float ex0 = acc[0];
#pragma unroll
    for (int e = 1; e < 8; e++) ex0 = fmaxf(ex0, acc[e]);
    float masked[8];
#pragma unroll
    for (int e = 0; e < 8; e++) masked[e] = (acc[e] == ex0) ? NEG_MIN : acc[e];
    float ex1 = masked[0];
#pragma unroll
    for (int e = 1; e < 8; e++) ex1 = fmaxf(ex1, masked[e]);
    float w0 = 1.f / (1.f + expf(ex1 - ex0));
#pragma unroll
    for (int e = 0; e < 8; e++) {
      float w = (acc[e] == ex0) ? w0 : ((masked[e] == ex1) ? (1.f - w0) : 0.f);
      wts[t * 8 + e] = w;
    }
  }
}

// ---------------------------------------------------------------------------
// Kernel 2: transpose + fp32->bf16.  src (R,C) fp32 row-major -> dst (C,R) bf16
// grid: (C/64, R/64, experts) x 256 threads.  64x64 tiles via LDS.
// ---------------------------------------------------------------------------
__global__ __launch_bounds__(256) void transpose_cvt_kernel(
    const float* __restrict__ src, u16* __restrict__ dst, int R, int C) {
  __shared__ u16 tile[64][68];   // +4 pad breaks bank alignment
  long eoff = (long)blockIdx.z * R * C;
  const float* s = src + eoff;
  u16* d = dst + eoff;
  int c0 = blockIdx.x * 64, r0 = blockIdx.y * 64;
  int tid = threadIdx.x;
#pragma unroll
  for (int p = 0; p < 4; p++) {
    int idx = tid + p * 256;
    int r = idx >> 4, c4 = (idx & 15) << 2;
    float4 v = *reinterpret_cast<const float4*>(s + (long)(r0 + r) * C + c0 + c4);
    ushort4 o = {f2bf(v.x), f2bf(v.y), f2bf(v.z), f2bf(v.w)};
    *reinterpret_cast<ushort4*>(&tile[r][c4]) = o;
  }
  __syncthreads();
#pragma unroll
  for (int p = 0; p < 4; p++) {
    int idx = tid + p * 256;
    int c = idx >> 4, r4 = (idx & 15) << 2;
    ushort4 o = {tile[r4][c], tile[r4 + 1][c], tile[r4 + 2][c], tile[r4 + 3][c]};
    *reinterpret_cast<ushort4*>(d + (long)(c0 + c) * R + r0 + r4) = o;
  }
}

// ---------------------------------------------------------------------------
// Kernel 3: h_e = silu(x @ w1[e]) * (x @ w3[e]), bf16 out.
// A = xb (T,H) bf16; B = w1t/w3t (F,H) bf16 (pre-transposed: rows K-contiguous).
// Block tile 128(M=t) x 64(N=f), BK=64.  4 waves in 2x2; wave = 64x32 = 4x2
// MFMA 16x16x32 tiles per path.  LDS rows padded to 72 elems (144B: 16B-aligned,
// word-stride 36 -> 2-way bank aliasing only, which is free).
// ---------------------------------------------------------------------------
__global__ __launch_bounds__(256, 2) void h_kernel(
    const u16* __restrict__ xb, const u16* __restrict__ w1t,
    const u16* __restrict__ w3t, u16* __restrict__ hout) {
  __shared__ u16 As[128 * 72];
  __shared__ u16 B1s[64 * 72];
  __shared__ u16 B3s[64 * 72];
  int f0 = blockIdx.x * 64;
  int t0 = blockIdx.y * 128;
  int el = blockIdx.z;   // expert (group-local)
  const u16* b1 = w1t + (long)el * F_DIM * H_DIM;
  const u16* b3 = w3t + (long)el * F_DIM * H_DIM;
  int tid = threadIdx.x;
  int wave = tid >> 6, lane = tid & 63;
  int wm = wave >> 1, wn = wave & 1;
  int mrow = lane & 15, quad = lane >> 4;

  f32x4 acc1[4][2], acc3[4][2];
#pragma unroll
  for (int mt = 0; mt < 4; mt++)
#pragma unroll
    for (int nt = 0; nt < 2; nt++) { acc1[mt][nt] = (f32x4)(0.f); acc3[mt][nt] = (f32x4)(0.f); }

  for (int kt = 0; kt < H_DIM; kt += 64) {
    // stage A: 128x64 bf16 (1024 16B-chunks)
#pragma unroll
    for (int it = 0; it < 4; it++) {
      int chunk = tid + it * 256;
      int r = chunk >> 3, c8 = (chunk & 7) << 3;
      uint4 v = *reinterpret_cast<const uint4*>(xb + (long)(t0 + r) * H_DIM + kt + c8);
      *reinterpret_cast<uint4*>(&As[r * 72 + c8]) = v;
    }
    // stage B1/B3: 64x64 bf16 each (512 chunks each)
#pragma unroll
    for (int it = 0; it < 2; it++) {
      int chunk = tid + it * 256;
      int r = chunk >> 3, c8 = (chunk & 7) << 3;
      long off = (long)(f0 + r) * H_DIM + kt + c8;
      uint4 v1 = *reinterpret_cast<const uint4*>(b1 + off);
      uint4 v3 = *reinterpret_cast<const uint4*>(b3 + off);
      *reinterpret_cast<uint4*>(&B1s[r * 72 + c8]) = v1;
      *reinterpret_cast<uint4*>(&B3s[r * 72 + c8]) = v3;
    }
    __syncthreads();
#pragma unroll
    for (int kh = 0; kh < 2; kh++) {
      int koff = kh * 32 + quad * 8;
      bf16x8 af[4], b1f[2], b3f[2];
#pragma unroll
      for (int mt = 0; mt < 4; mt++)
        af[mt] = *reinterpret_cast<const bf16x8*>(&As[(wm * 64 + mt * 16 + mrow) * 72 + koff]);
#pragma unroll
      for (int nt = 0; nt < 2; nt++) {
        b1f[nt] = *reinterpret_cast<const bf16x8*>(&B1s[(wn * 32 + nt * 16 + mrow) * 72 + koff]);
        b3f[nt] = *reinterpret_cast<const bf16x8*>(&B3s[(wn * 32 + nt * 16 + mrow) * 72 + koff]);
      }
#pragma unroll
      for (int mt = 0; mt < 4; mt++)
#pragma unroll
        for (int nt = 0; nt < 2; nt++) {
          acc1[mt][nt] = __builtin_amdgcn_mfma_f32_16x16x32_bf16(af[mt], b1f[nt], acc1[mt][nt], 0, 0, 0);
          acc3[mt][nt] = __builtin_amdgcn_mfma_f32_16x16x32_bf16(af[mt], b3f[nt], acc3[mt][nt], 0, 0, 0);
        }
    }
    __syncthreads();
  }
  // epilogue: SwiGLU, write bf16.  C/D layout: col=lane&15, row=quad*4+reg.
  u16* hp = hout + (long)el * T_DIM * F_DIM;
#pragma unroll
  for (int mt = 0; mt < 4; mt++) {
#pragma unroll
    for (int r = 0; r < 4; r++) {
      int row = t0 + wm * 64 + mt * 16 + quad * 4 + r;
#pragma unroll
      for (int nt = 0; nt < 2; nt++) {
        int col = f0 + wn * 32 + nt * 16 + mrow;
        float v1 = acc1[mt][nt][r];
        float v3 = acc3[mt][nt][r];
        float sw = (v1 / (1.f + expf(-v1))) * v3;
        hp[(long)row * F_DIM + col] = f2bf(sw);
      }
    }
  }
}

// ---------------------------------------------------------------------------
// Kernel 4: out[t,hh] += wts[t,e] * (h_e @ w2[e])[t,hh]
// A = h_e (T,F) bf16; B = w2t (H,F) bf16.  Same tiling as h_kernel, single path.
// Split over experts (grid.z) with fp32 atomic accumulation into zeroed out.
// ---------------------------------------------------------------------------
__global__ __launch_bounds__(256, 2) void y_kernel(
    const u16* __restrict__ h, const u16* __restrict__ w2t,
    const float* __restrict__ wts, float* __restrict__ out, int e_base) {
  __shared__ u16 As[128 * 72];
  __shared__ u16 Bs[64 * 72];
  int n0 = blockIdx.x * 64;
  int t0 = blockIdx.y * 128;
  int el = blockIdx.z;
  int eg = e_base + el;
  const u16* a = h + (long)el * T_DIM * F_DIM;
  const u16* b = w2t + (long)el * H_DIM * F_DIM;
  int tid = threadIdx.x;
  int wave = tid >> 6, lane = tid & 63;
  int wm = wave >> 1, wn = wave & 1;
  int mrow = lane & 15, quad = lane >> 4;

  f32x4 acc[4][2];
#pragma unroll
  for (int mt = 0; mt < 4; mt++)
#pragma unroll
    for (int nt = 0; nt < 2; nt++) acc[mt][nt] = (f32x4)(0.f);

  for (int kt = 0; kt < F_DIM; kt += 64) {
#pragma unroll
    for (int it = 0; it < 4; it++) {
      int chunk = tid + it * 256;
      int r = chunk >> 3, c8 = (chunk & 7) << 3;
      uint4 v = *reinterpret_cast<const uint4*>(a + (long)(t0 + r) * F_DIM + kt + c8);
      *reinterpret_cast<uint4*>(&As[r * 72 + c8]) = v;
    }
#pragma unroll
    for (int it = 0; it < 2; it++) {
      int chunk = tid + it * 256;
      int r = chunk >> 3, c8 = (chunk & 7) << 3;
      uint4 v = *reinterpret_cast<const uint4*>(b + (long)(n0 + r) * F_DIM + kt + c8);
      *reinterpret_cast<uint4*>(&Bs[r * 72 + c8]) = v;
    }
    __syncthreads();
#pragma unroll
    for (int kh = 0; kh < 2; kh++) {
      int koff = kh * 32 + quad * 8;
      bf16x8 af[4], bf[2];
#pragma unroll
      for (int mt = 0; mt < 4; mt++)
        af[mt] = *reinterpret_cast<const bf16x8*>(&As[(wm * 64 + mt * 16 + mrow) * 72 + koff]);
#pragma unroll
      for (int nt = 0; nt < 2; nt++)
        bf[nt] = *reinterpret_cast<const bf16x8*>(&Bs[(wn * 32 + nt * 16 + mrow) * 72 + koff]);
#pragma unroll
      for (int mt = 0; mt < 4; mt++)
#pragma unroll
        for (int nt = 0; nt < 2; nt++)
          acc[mt][nt] = __builtin_amdgcn_mfma_f32_16x16x32_bf16(af[mt], bf[nt], acc[mt][nt], 0, 0, 0);
    }
    __syncthreads();
  }
#pragma unroll
  for (int mt = 0; mt < 4; mt++) {
#pragma unroll
    for (int r = 0; r < 4; r++) {
      int row = t0 + wm * 64 + mt * 16 + quad * 4 + r;
      float wt = wts[row * 8 + eg];
#pragma unroll
      for (int nt = 0; nt < 2; nt++) {
        int col = n0 + wn * 32 + nt * 16 + mrow;
        unsafeAtomicAdd(&out[(long)row * H_DIM + col], acc[mt][nt][r] * wt);
      }
    }
  }
}

// ---------------------------------------------------------------------------
extern "C" void kernel_launch(void* const* d_in, const int* in_sizes, int n_in,
                              void* d_out, int out_size, void* d_ws, size_t ws_size,
                              hipStream_t stream) {
  const float* x  = (const float*)d_in[0];
  const float* wg = (const float*)d_in[1];
  const float* w1 = (const float*)d_in[2];
  const float* w3 = (const float*)d_in[3];
  const float* w2 = (const float*)d_in[4];
  float* out = (float*)d_out;

  char* p = (char*)d_ws;
  u16* xb = (u16*)p;            p += (size_t)T_DIM * H_DIM * 2;
  float* wts = (float*)p;       p += (size_t)T_DIM * E_DIM * 4;
  size_t fixed = (size_t)(p - (char*)d_ws);
  size_t perE = (size_t)F_DIM * H_DIM * 2 * 3 + (size_t)T_DIM * F_DIM * 2;
  int G = 1;
  for (int g = 8; g >= 1; g >>= 1) {
    if (fixed + (size_t)g * perE <= ws_size) { G = g; break; }
  }
  u16* w1t = (u16*)p;           p += (size_t)G * F_DIM * H_DIM * 2;
  u16* w3t = (u16*)p;           p += (size_t)G * F_DIM * H_DIM * 2;
  u16* w2t = (u16*)p;           p += (size_t)G * H_DIM * F_DIM * 2;
  u16* hbuf = (u16*)p;

  gate_cvt_kernel<<<T_DIM / 4, 256, 0, stream>>>(x, wg, xb, wts);
  hipMemsetAsync(d_out, 0, (size_t)out_size * 4, stream);

  for (int e0 = 0; e0 < E_DIM; e0 += G) {
    transpose_cvt_kernel<<<dim3(F_DIM / 64, H_DIM / 64, G), 256, 0, stream>>>(
        w1 + (size_t)e0 * H_DIM * F_DIM, w1t, H_DIM, F_DIM);
    transpose_cvt_kernel<<<dim3(F_DIM / 64, H_DIM / 64, G), 256, 0, stream>>>(
        w3 + (size_t)e0 * H_DIM * F_DIM, w3t, H_DIM, F_DIM);
    transpose_cvt_kernel<<<dim3(H_DIM / 64, F_DIM / 64, G), 256, 0, stream>>>(
        w2 + (size_t)e0 * F_DIM * H_DIM, w2t, F_DIM, H_DIM);
    h_kernel<<<dim3(F_DIM / 64, T_DIM / 128, G), 256, 0, stream>>>(xb, w1t, w3t, hbuf);
    y_kernel<<<dim3(H_DIM / 64, T_DIM / 128, G), 256, 0, stream>>>(hbuf, w2t, wts, out, e0);
  }
}